// Round 5
// baseline (234.853 us; speedup 1.0000x reference)
//
#include <hip/hip_runtime.h>
#include <hip/hip_bf16.h>
#include <math.h>

typedef __bf16 bf16;
typedef __bf16 bf16x8 __attribute__((ext_vector_type(8)));
typedef __bf16 bf16x4 __attribute__((ext_vector_type(4)));
typedef float f32x4 __attribute__((ext_vector_type(4)));

#define EPSc 1.1920929e-07f
#define LOG2E 1.44269504f

static __device__ __forceinline__ void glds16(const void* g, void* l) {
  __builtin_amdgcn_global_load_lds((const __attribute__((address_space(1))) void*)g,
                                   (__attribute__((address_space(3))) void*)l, 16, 0, 0);
}

static __device__ __forceinline__ bf16x4 comb4(const float* b0, const float* b1,
                                               const float* b2, const float* b3,
                                               float a0, float a1, float a2, float a3) {
  float4 v0 = *(const float4*)b0, v1 = *(const float4*)b1;
  float4 v2 = *(const float4*)b2, v3 = *(const float4*)b3;
  bf16x4 o;
  o[0] = (bf16)(a0*v0.x + a1*v1.x + a2*v2.x + a3*v3.x);
  o[1] = (bf16)(a0*v0.y + a1*v1.y + a2*v2.y + a3*v3.y);
  o[2] = (bf16)(a0*v0.z + a1*v1.z + a2*v2.z + a3*v3.z);
  o[3] = (bf16)(a0*v0.w + a1*v1.w + a2*v2.w + a3*v3.w);
  return o;
}

// ---- prep1: fused combine_qkv + combine_o + rmsnorm1 (all independent) -------------
__global__ __launch_bounds__(256)
void prep1(const float* __restrict__ qkv_b, const float* __restrict__ a_qkv,
           const float* __restrict__ o_b,   const float* __restrict__ a_o,
           const float* __restrict__ x, const float* __restrict__ n1w,
           const float* __restrict__ gamma, const float* __restrict__ beta,
           const int* __restrict__ lidx,
           bf16* __restrict__ Wqkv, bf16* __restrict__ Wo, bf16* __restrict__ hbuf) {
  const int bid = blockIdx.x, tid = threadIdx.x;
  if (bid < 4096) {
    int li = lidx[0];
    const float* base; const float* al; bf16* out; size_t flat, n;
    if (bid < 3072) { base = qkv_b; al = a_qkv; out = Wqkv; flat = (size_t)bid << 10; n = (size_t)3072*1024; }
    else            { base = o_b;   al = a_o;   out = Wo;   flat = (size_t)(bid-3072) << 10; n = (size_t)1024*1024; }
    float a0 = al[li*4], a1 = al[li*4+1], a2 = al[li*4+2], a3 = al[li*4+3];
    size_t off = flat + tid*4;
    bf16x4 o = comb4(base+off, base+n+off, base+2*n+off, base+3*n+off, a0, a1, a2, a3);
    *(bf16x4*)&out[off] = o;
  } else {
    int row = bid - 4096, t = tid;
    const float4* xr = (const float4*)(x + (size_t)row*1024);
    float4 v = xr[t];
    float ss = v.x*v.x + v.y*v.y + v.z*v.z + v.w*v.w;
    #pragma unroll
    for (int off = 32; off > 0; off >>= 1) ss += __shfl_down(ss, off, 64);
    __shared__ float red[4];
    if ((t & 63) == 0) red[t >> 6] = ss;
    __syncthreads();
    float tot = red[0] + red[1] + red[2] + red[3];
    float r = rsqrtf(tot * (1.0f/1024.0f) + EPSc);
    float4 wv = ((const float4*)n1w)[t];
    float4 gv = ((const float4*)gamma)[t];
    float4 bv = ((const float4*)beta)[t];
    bf16x4 o;
    o[0] = (bf16)(v.x*r*wv.x*gv.x + bv.x);
    o[1] = (bf16)(v.y*r*wv.y*gv.y + bv.y);
    o[2] = (bf16)(v.z*r*wv.z*gv.z + bv.z);
    o[3] = (bf16)(v.w*r*wv.w*gv.w + bv.w);
    *(bf16x4*)&hbuf[(size_t)row*1024 + t*4] = o;
  }
}

// ---------------- rmsnorm (standalone, for norm2) ------------------------------------
__global__ __launch_bounds__(256) void rmsnorm_k(const float* __restrict__ x,
                                                 const float* __restrict__ w,
                                                 const float* __restrict__ gamma,
                                                 const float* __restrict__ beta,
                                                 bf16* __restrict__ out) {
  int row = blockIdx.x, t = threadIdx.x;
  const float4* xr = (const float4*)(x + (size_t)row*1024);
  float4 v = xr[t];
  float ss = v.x*v.x + v.y*v.y + v.z*v.z + v.w*v.w;
  #pragma unroll
  for (int off = 32; off > 0; off >>= 1) ss += __shfl_down(ss, off, 64);
  __shared__ float red[4];
  if ((t & 63) == 0) red[t >> 6] = ss;
  __syncthreads();
  float tot = red[0] + red[1] + red[2] + red[3];
  float r = rsqrtf(tot * (1.0f/1024.0f) + EPSc);
  float4 wv = ((const float4*)w)[t];
  float4 gv = ((const float4*)gamma)[t];
  float4 bv = ((const float4*)beta)[t];
  bf16x4 o;
  o[0] = (bf16)(v.x*r*wv.x*gv.x + bv.x);
  o[1] = (bf16)(v.y*r*wv.y*gv.y + bv.y);
  o[2] = (bf16)(v.z*r*wv.z*gv.z + bv.z);
  o[3] = (bf16)(v.w*r*wv.w*gv.w + bv.w);
  *(bf16x4*)&out[(size_t)row*1024 + t*4] = o;
}

// ---------------- GEMM: C[M,N] = A[M,K] * B[N,K]^T, bf16 in, fp32 acc ----------------
// EP: 0 = store bf16; 1 = fp32 + auxf residual; 4 = x+(xa+acc-x)*s; 5 = silu-gate*up;
//     6 = plain fp32 store (split-K partial)
template<int EP, int NTW>
__global__ __launch_bounds__(256)
void gemm_bt(const bf16* __restrict__ A, const bf16* __restrict__ Bw,
             int M, int N, int K, int lda, int ldb, int gx,
             float* __restrict__ outf, bf16* __restrict__ outb,
             const float* __restrict__ auxf, const float* __restrict__ auxf2,
             const float* __restrict__ iscale) {
  constexpr int BN = NTW * 32;
  __shared__ __align__(16) bf16 As[2][128*64];
  __shared__ __align__(16) bf16 Bs[2][BN*64];
  const int nwg = gridDim.x;
  const int orig = blockIdx.x;
  const int wg = (orig & 7) * (nwg >> 3) + (orig >> 3);
  const int tn0 = (wg % gx) * BN, tm0 = (wg / gx) * 128;
  const int tid = threadIdx.x, wave = tid >> 6, lane = tid & 63;
  const int lr = lane & 15, lg = lane >> 4;
  const int wr = wave >> 1, wc = wave & 1;
  f32x4 acc[4][NTW] = {};
  const int rs = lane >> 3, cs = (lane & 7) * 8;

  const bf16* Abase = A + (size_t)tm0 * lda;
  const bf16* Bbase = Bw + (size_t)tn0 * ldb;

  auto stage = [&](bf16* as, bf16* bs, int k0) {
    #pragma unroll
    for (int j = 0; j < 4; ++j) {
      int chunk = wave*4 + j;
      int r = chunk*8 + rs;
      glds16(Abase + (size_t)r*lda + k0 + cs, as + chunk*512 + lane*8);
    }
    #pragma unroll
    for (int j = 0; j < NTW; ++j) {
      int chunk = wave*NTW + j;
      int r = chunk*8 + rs;
      glds16(Bbase + (size_t)r*ldb + k0 + cs, bs + chunk*512 + lane*8);
    }
  };
  auto comp = [&](const bf16* as, const bf16* bs) {
    #pragma unroll
    for (int kk = 0; kk < 2; ++kk) {
      bf16x8 av[4], bv[NTW];
      #pragma unroll
      for (int m = 0; m < 4; ++m) av[m] = *(const bf16x8*)&as[(wr*64 + m*16 + lr)*64 + kk*32 + lg*8];
      #pragma unroll
      for (int n = 0; n < NTW; ++n) bv[n] = *(const bf16x8*)&bs[(wc*NTW*16 + n*16 + lr)*64 + kk*32 + lg*8];
      #pragma unroll
      for (int m = 0; m < 4; ++m)
        #pragma unroll
        for (int n = 0; n < NTW; ++n)
          acc[m][n] = __builtin_amdgcn_mfma_f32_16x16x32_bf16(av[m], bv[n], acc[m][n], 0, 0, 0);
    }
  };

  bf16 *a0 = As[0], *a1 = As[1], *b0 = Bs[0], *b1 = Bs[1];
  stage(a0, b0, 0);
  __syncthreads();
  for (int k0 = 64; k0 < K; k0 += 64) {
    stage(a1, b1, k0);
    comp(a0, b0);
    __syncthreads();
    bf16* t;
    t = a0; a0 = a1; a1 = t;
    t = b0; b0 = b1; b1 = t;
  }
  comp(a0, b0);

  float its = 0.f;
  if constexpr (EP == 4) its = iscale[0];

  if constexpr (EP == 5) {
    #pragma unroll
    for (int m = 0; m < 4; ++m)
      #pragma unroll
      for (int j = 0; j < NTW/2; ++j)
        #pragma unroll
        for (int i = 0; i < 4; ++i) {
          int row = tm0 + wr*64 + m*16 + lg*4 + i;
          int col = (tn0 >> 1) + wc*(NTW*8) + j*16 + lr;
          float g = acc[m][2*j][i], u = acc[m][2*j+1][i];
          float s = g / (1.f + __builtin_amdgcn_exp2f(-g * LOG2E));
          outb[(size_t)row * (N >> 1) + col] = (bf16)(s * u);
        }
  } else {
    #pragma unroll
    for (int m = 0; m < 4; ++m)
      #pragma unroll
      for (int n = 0; n < NTW; ++n)
        #pragma unroll
        for (int i = 0; i < 4; ++i) {
          int row = tm0 + wr*64 + m*16 + lg*4 + i;
          int col = tn0 + wc*NTW*16 + n*16 + lr;
          size_t idx = (size_t)row * N + col;
          float v = acc[m][n][i];
          if constexpr (EP == 0) outb[idx] = (bf16)v;
          else if constexpr (EP == 1) outf[idx] = auxf[idx] + v;
          else if constexpr (EP == 4) {
            float xv = auxf[idx], xa = auxf2[idx];
            outf[idx] = xv + (xa + v - xv) * its;
          } else if constexpr (EP == 6) outf[idx] = v;
        }
  }
}

// ---- final: out = x + (xat + p0 + p1 - x) * iter_scale ------------------------------
__global__ __launch_bounds__(256)
void reduce2(const float* __restrict__ p0, const float* __restrict__ p1,
             const float* __restrict__ x, const float* __restrict__ xat,
             const float* __restrict__ iscale, float* __restrict__ out) {
  size_t i = (size_t)blockIdx.x * 256 + threadIdx.x;
  float its = iscale[0];
  float4 a = ((const float4*)p0)[i], b = ((const float4*)p1)[i];
  float4 xv = ((const float4*)x)[i], xa = ((const float4*)xat)[i];
  float4 o;
  o.x = xv.x + (xa.x + a.x + b.x - xv.x) * its;
  o.y = xv.y + (xa.y + a.y + b.y - xv.y) * its;
  o.z = xv.z + (xa.z + a.z + b.z - xv.z) * its;
  o.w = xv.w + (xa.w + a.w + b.w - xv.w) * its;
  ((float4*)out)[i] = o;
}

// ---- mega-kernel: gu/down weight combine (bids 0..255, FIRST for residency) + attn --
__global__ __launch_bounds__(256)
void attn_mega(const bf16* __restrict__ qkv, bf16* __restrict__ out,
               const float* __restrict__ gate_b, const float* __restrict__ up_b,
               const float* __restrict__ down_b,
               const float* __restrict__ a_gate, const float* __restrict__ a_up,
               const float* __restrict__ a_down, const int* __restrict__ lidx,
               bf16* __restrict__ Wgu, bf16* __restrict__ Wd) {
  __shared__ __align__(16) bf16 Ks[2][64*72];
  __shared__ __align__(16) bf16 Vt[2][64*66];
  __shared__ __align__(16) bf16 Ps[4][16*68];
  const int bid = blockIdx.x;
  const int tid = threadIdx.x;

  if (bid < 256) {
    // combine path: 12288 row-chunks over 256 blocks, stride-interleaved
    const int cb = bid;
    int li = lidx[0];
    float g0 = a_gate[li*4], g1 = a_gate[li*4+1], g2 = a_gate[li*4+2], g3 = a_gate[li*4+3];
    float u0 = a_up[li*4],   u1 = a_up[li*4+1],   u2 = a_up[li*4+2],   u3 = a_up[li*4+3];
    float d0 = a_down[li*4], d1 = a_down[li*4+1], d2 = a_down[li*4+2], d3 = a_down[li*4+3];
    const size_t PS = (size_t)4096 * 1024;
    for (int it = 0; it < 48; ++it) {
      int chunk = it * 256 + cb;
      if (chunk < 8192) {
        int r = chunk, w = r & 31;
        int f = ((r >> 5) << 4) + (w & 15);
        const float* base = (w < 16) ? gate_b : up_b;
        float a0 = (w < 16) ? g0 : u0, a1 = (w < 16) ? g1 : u1;
        float a2 = (w < 16) ? g2 : u2, a3 = (w < 16) ? g3 : u3;
        size_t src = (size_t)f*1024 + tid*4;
        bf16x4 o = comb4(base+src, base+PS+src, base+2*PS+src, base+3*PS+src, a0, a1, a2, a3);
        *(bf16x4*)&Wgu[((size_t)r << 10) + tid*4] = o;
      } else {
        size_t off = ((size_t)(chunk - 8192) << 10) + tid*4;
        bf16x4 o = comb4(down_b+off, down_b+PS+off, down_b+2*PS+off, down_b+3*PS+off, d0, d1, d2, d3);
        *(bf16x4*)&Wd[off] = o;
      }
    }
    return;
  }

  // ---------------- attention path: causal flash, H=16 T=2048 HD=64 ----------------
  const int a = bid - 256;
  const int qb = 31 - (a >> 4);
  const int h = (a & 7) + 8 * ((a >> 3) & 1);
  const int wave = tid >> 6, lane = tid & 63;
  const int lr = lane & 15, lg = lane >> 4;
  const int q0 = qb * 64;

  bf16x8 qf[2];
  {
    const bf16* qrow = qkv + (size_t)(q0 + wave*16 + lr)*3072 + h*64;
    qf[0] = *(const bf16x8*)(qrow + lg*8);
    qf[1] = *(const bf16x8*)(qrow + 32 + lg*8);
  }
  f32x4 o[4] = {};
  float mrow[4], lrow[4];
  #pragma unroll
  for (int i = 0; i < 4; ++i) { mrow[i] = -__builtin_inff(); lrow[i] = 0.f; }

  const int r0 = tid >> 3, r1 = (tid + 256) >> 3;
  const int c0 = (tid & 7) << 3;
  const bf16* kb = qkv + 1024 + h*64 + c0;
  const bf16* vb = qkv + 2048 + h*64 + c0;

  bf16x8 kreg[2], vreg[2];
  auto stage_load = [&](int kv0) {
    kreg[0] = *(const bf16x8*)(kb + (size_t)(kv0 + r0)*3072);
    kreg[1] = *(const bf16x8*)(kb + (size_t)(kv0 + r1)*3072);
    vreg[0] = *(const bf16x8*)(vb + (size_t)(kv0 + r0)*3072);
    vreg[1] = *(const bf16x8*)(vb + (size_t)(kv0 + r1)*3072);
  };
  auto stage_write = [&](int buf) {
    *(bf16x8*)&Ks[buf][r0*72 + c0] = kreg[0];
    *(bf16x8*)&Ks[buf][r1*72 + c0] = kreg[1];
    #pragma unroll
    for (int e = 0; e < 8; ++e) Vt[buf][(c0 + e)*66 + r0] = vreg[0][e];
    #pragma unroll
    for (int e = 0; e < 8; ++e) Vt[buf][(c0 + e)*66 + r1] = vreg[1][e];
  };

  stage_load(0);
  stage_write(0);
  __syncthreads();
  int cur = 0;

  const float C = 0.125f * LOG2E;   // scale folded with log2(e); scores kept raw

  for (int t = 0; t <= qb; ++t) {
    const int kv0 = t * 64;
    if (t < qb) stage_load(kv0 + 64);

    f32x4 s[4] = {};
    __builtin_amdgcn_s_setprio(1);
    #pragma unroll
    for (int n = 0; n < 4; ++n) {
      bf16x8 k0f = *(const bf16x8*)&Ks[cur][(n*16 + lr)*72 + lg*8];
      s[n] = __builtin_amdgcn_mfma_f32_16x16x32_bf16(qf[0], k0f, s[n], 0, 0, 0);
      bf16x8 k1f = *(const bf16x8*)&Ks[cur][(n*16 + lr)*72 + 32 + lg*8];
      s[n] = __builtin_amdgcn_mfma_f32_16x16x32_bf16(qf[1], k1f, s[n], 0, 0, 0);
    }
    __builtin_amdgcn_s_setprio(0);

    if (t == qb) {                          // mask only the diagonal tile
      const int qbase = q0 + wave*16 + lg*4;
      #pragma unroll
      for (int n = 0; n < 4; ++n)
        #pragma unroll
        for (int i = 0; i < 4; ++i)
          if (kv0 + n*16 + lr > qbase + i) s[n][i] = -__builtin_inff();
    }

    float mnewr[4], pmn[4];
    #pragma unroll
    for (int i = 0; i < 4; ++i) mnewr[i] = fmaxf(fmaxf(s[0][i], s[1][i]), fmaxf(s[2][i], s[3][i]));
    #pragma unroll
    for (int i = 0; i < 4; ++i)
      #pragma unroll
      for (int off = 1; off < 16; off <<= 1) mnewr[i] = fmaxf(mnewr[i], __shfl_xor(mnewr[i], off, 64));
    bool grow = false;
    #pragma unroll
    for (int i = 0; i < 4; ++i) { pmn[i] = mnewr[i] * C; grow = grow || (pmn[i] > mrow[i] + 8.f); }
    if (__any(grow)) {                      // defer-max: rescale only on real growth
      #pragma unroll
      for (int i = 0; i < 4; ++i) {
        float mt = fmaxf(mrow[i], pmn[i]);
        float fc = __builtin_amdgcn_exp2f(mrow[i] - mt);
        mrow[i] = mt;
        lrow[i] *= fc;
        #pragma unroll
        for (int nd = 0; nd < 4; ++nd) o[nd][i] *= fc;
      }
    }
    float rsum[4] = {0.f, 0.f, 0.f, 0.f};
    #pragma unroll
    for (int n = 0; n < 4; ++n)
      #pragma unroll
      for (int i = 0; i < 4; ++i) {
        float e = __builtin_amdgcn_exp2f(__builtin_fmaf(s[n][i], C, -mrow[i]));
        s[n][i] = e;
        rsum[i] += e;
      }
    #pragma unroll
    for (int i = 0; i < 4; ++i)
      #pragma unroll
      for (int off = 1; off < 16; off <<= 1) rsum[i] += __shfl_xor(rsum[i], off, 64);
    #pragma unroll
    for (int i = 0; i < 4; ++i) lrow[i] += rsum[i];
    #pragma unroll
    for (int n = 0; n < 4; ++n)
      #pragma unroll
      for (int i = 0; i < 4; ++i) Ps[wave][(lg*4 + i)*68 + n*16 + lr] = (bf16)s[n][i];
    asm volatile("s_waitcnt lgkmcnt(0)" ::: "memory");
    __builtin_amdgcn_s_setprio(1);
    #pragma unroll
    for (int kk = 0; kk < 2; ++kk) {
      bf16x8 pf = *(const bf16x8*)&Ps[wave][lr*68 + kk*32 + lg*8];
      #pragma unroll
      for (int nd = 0; nd < 4; ++nd) {
        bf16x8 vf = *(const bf16x8*)&Vt[cur][(nd*16 + lr)*66 + kk*32 + lg*8];
        o[nd] = __builtin_amdgcn_mfma_f32_16x16x32_bf16(pf, vf, o[nd], 0, 0, 0);
      }
    }
    __builtin_amdgcn_s_setprio(0);
    if (t < qb) {
      stage_write(cur ^ 1);
      __syncthreads();
      cur ^= 1;
    }
  }
  #pragma unroll
  for (int i = 0; i < 4; ++i) {
    float inv = 1.f / lrow[i];
    #pragma unroll
    for (int nd = 0; nd < 4; ++nd)
      out[(size_t)(q0 + wave*16 + lg*4 + i)*1024 + h*64 + nd*16 + lr] = (bf16)(o[nd][i]*inv);
  }
}

extern "C" void kernel_launch(void* const* d_in, const int* in_sizes, int n_in,
                              void* d_out, int out_size, void* d_ws, size_t ws_size,
                              hipStream_t stream) {
  const float* x        = (const float*)d_in[0];
  const float* gamma    = (const float*)d_in[1];
  const float* beta     = (const float*)d_in[2];
  const float* iscale   = (const float*)d_in[3];
  const float* qkv_b    = (const float*)d_in[4];
  const float* o_b      = (const float*)d_in[5];
  const float* gate_b   = (const float*)d_in[6];
  const float* up_b     = (const float*)d_in[7];
  const float* down_b   = (const float*)d_in[8];
  const float* a_qkv    = (const float*)d_in[9];
  const float* a_o      = (const float*)d_in[10];
  const float* a_gate   = (const float*)d_in[11];
  const float* a_up     = (const float*)d_in[12];
  const float* a_down   = (const float*)d_in[13];
  const float* n1w      = (const float*)d_in[14];
  const float* n2w      = (const float*)d_in[15];
  const int*   lidx     = (const int*)d_in[16];

  char* p = (char*)d_ws;
  auto alloc = [&](size_t bytes) { char* r = p; p += (bytes + 255) & ~(size_t)255; return r; };
  bf16*  Wqkv = (bf16*)alloc((size_t)3072*1024*2);
  bf16*  Wo   = (bf16*)alloc((size_t)1024*1024*2);
  bf16*  Wgu  = (bf16*)alloc((size_t)8192*1024*2);
  bf16*  Wd   = (bf16*)alloc((size_t)1024*4096*2);
  bf16*  hbuf = (bf16*)alloc((size_t)2048*1024*2);
  bf16*  qkvb = (bf16*)alloc((size_t)2048*3072*2);
  bf16*  attn = (bf16*)alloc((size_t)2048*1024*2);
  float* xat  = (float*)alloc((size_t)2048*1024*4);
  bf16*  h2   = (bf16*)alloc((size_t)2048*1024*2);
  bf16*  act  = (bf16*)alloc((size_t)2048*4096*2);
  float* out  = (float*)d_out;
  // split-K partials alias workspace that is dead by the time down-GEMM runs:
  // p0 over Wqkv+Wo (8 MB), p1 over qkvb (12 MB)
  float* part0 = (float*)Wqkv;
  float* part1 = (float*)qkvb;

  prep1<<<6144, 256, 0, stream>>>(qkv_b, a_qkv, o_b, a_o, x, n1w, gamma, beta, lidx,
                                  Wqkv, Wo, hbuf);
  gemm_bt<0,4><<<24*16, 256, 0, stream>>>(hbuf, Wqkv, 2048, 3072, 1024, 1024, 1024, 24,
                                          nullptr, qkvb, nullptr, nullptr, nullptr);
  attn_mega<<<768, 256, 0, stream>>>(qkvb, attn, gate_b, up_b, down_b,
                                     a_gate, a_up, a_down, lidx, Wgu, Wd);
  gemm_bt<1,2><<<16*16, 256, 0, stream>>>(attn, Wo, 2048, 1024, 1024, 1024, 1024, 16,
                                          xat, nullptr, x, nullptr, nullptr);
  rmsnorm_k<<<2048, 256, 0, stream>>>(xat, n2w, gamma, beta, h2);
  gemm_bt<5,4><<<64*16, 256, 0, stream>>>(h2, Wgu, 2048, 8192, 1024, 1024, 1024, 64,
                                          nullptr, act, nullptr, nullptr, nullptr);
  gemm_bt<6,2><<<16*16, 256, 0, stream>>>(act, Wd, 2048, 1024, 2048, 4096, 4096, 16,
                                          part0, nullptr, nullptr, nullptr, nullptr);
  gemm_bt<6,2><<<16*16, 256, 0, stream>>>(act + 2048, Wd + 2048, 2048, 1024, 2048, 4096, 4096, 16,
                                          part1, nullptr, nullptr, nullptr, nullptr);
  reduce2<<<2048, 256, 0, stream>>>(part0, part1, x, xat, iscale, out);
}

// Round 6
// 203.962 us; speedup vs baseline: 1.1515x; 1.1515x over previous
//
#include <hip/hip_runtime.h>
#include <hip/hip_bf16.h>
#include <math.h>

typedef __bf16 bf16;
typedef __bf16 bf16x8 __attribute__((ext_vector_type(8)));
typedef __bf16 bf16x4 __attribute__((ext_vector_type(4)));
typedef float f32x4 __attribute__((ext_vector_type(4)));

#define EPSc 1.1920929e-07f
#define LOG2E 1.44269504f

static __device__ __forceinline__ void glds16(const void* g, void* l) {
  __builtin_amdgcn_global_load_lds((const __attribute__((address_space(1))) void*)g,
                                   (__attribute__((address_space(3))) void*)l, 16, 0, 0);
}

static __device__ __forceinline__ bf16x4 comb4(const float* b0, const float* b1,
                                               const float* b2, const float* b3,
                                               float a0, float a1, float a2, float a3) {
  float4 v0 = *(const float4*)b0, v1 = *(const float4*)b1;
  float4 v2 = *(const float4*)b2, v3 = *(const float4*)b3;
  bf16x4 o;
  o[0] = (bf16)(a0*v0.x + a1*v1.x + a2*v2.x + a3*v3.x);
  o[1] = (bf16)(a0*v0.y + a1*v1.y + a2*v2.y + a3*v3.y);
  o[2] = (bf16)(a0*v0.z + a1*v1.z + a2*v2.z + a3*v3.z);
  o[3] = (bf16)(a0*v0.w + a1*v1.w + a2*v2.w + a3*v3.w);
  return o;
}

// ---- prep1: fused combine_qkv + combine_o + rmsnorm1 (all independent) -------------
__global__ __launch_bounds__(256)
void prep1(const float* __restrict__ qkv_b, const float* __restrict__ a_qkv,
           const float* __restrict__ o_b,   const float* __restrict__ a_o,
           const float* __restrict__ x, const float* __restrict__ n1w,
           const float* __restrict__ gamma, const float* __restrict__ beta,
           const int* __restrict__ lidx,
           bf16* __restrict__ Wqkv, bf16* __restrict__ Wo, bf16* __restrict__ hbuf) {
  const int bid = blockIdx.x, tid = threadIdx.x;
  if (bid < 4096) {
    int li = lidx[0];
    const float* base; const float* al; bf16* out; size_t flat, n;
    if (bid < 3072) { base = qkv_b; al = a_qkv; out = Wqkv; flat = (size_t)bid << 10; n = (size_t)3072*1024; }
    else            { base = o_b;   al = a_o;   out = Wo;   flat = (size_t)(bid-3072) << 10; n = (size_t)1024*1024; }
    float a0 = al[li*4], a1 = al[li*4+1], a2 = al[li*4+2], a3 = al[li*4+3];
    size_t off = flat + tid*4;
    bf16x4 o = comb4(base+off, base+n+off, base+2*n+off, base+3*n+off, a0, a1, a2, a3);
    *(bf16x4*)&out[off] = o;
  } else {
    int row = bid - 4096, t = tid;
    const float4* xr = (const float4*)(x + (size_t)row*1024);
    float4 v = xr[t];
    float ss = v.x*v.x + v.y*v.y + v.z*v.z + v.w*v.w;
    #pragma unroll
    for (int off = 32; off > 0; off >>= 1) ss += __shfl_down(ss, off, 64);
    __shared__ float red[4];
    if ((t & 63) == 0) red[t >> 6] = ss;
    __syncthreads();
    float tot = red[0] + red[1] + red[2] + red[3];
    float r = rsqrtf(tot * (1.0f/1024.0f) + EPSc);
    float4 wv = ((const float4*)n1w)[t];
    float4 gv = ((const float4*)gamma)[t];
    float4 bv = ((const float4*)beta)[t];
    bf16x4 o;
    o[0] = (bf16)(v.x*r*wv.x*gv.x + bv.x);
    o[1] = (bf16)(v.y*r*wv.y*gv.y + bv.y);
    o[2] = (bf16)(v.z*r*wv.z*gv.z + bv.z);
    o[3] = (bf16)(v.w*r*wv.w*gv.w + bv.w);
    *(bf16x4*)&hbuf[(size_t)row*1024 + t*4] = o;
  }
}

// ---------------- rmsnorm (standalone, for norm2) ------------------------------------
__global__ __launch_bounds__(256) void rmsnorm_k(const float* __restrict__ x,
                                                 const float* __restrict__ w,
                                                 const float* __restrict__ gamma,
                                                 const float* __restrict__ beta,
                                                 bf16* __restrict__ out) {
  int row = blockIdx.x, t = threadIdx.x;
  const float4* xr = (const float4*)(x + (size_t)row*1024);
  float4 v = xr[t];
  float ss = v.x*v.x + v.y*v.y + v.z*v.z + v.w*v.w;
  #pragma unroll
  for (int off = 32; off > 0; off >>= 1) ss += __shfl_down(ss, off, 64);
  __shared__ float red[4];
  if ((t & 63) == 0) red[t >> 6] = ss;
  __syncthreads();
  float tot = red[0] + red[1] + red[2] + red[3];
  float r = rsqrtf(tot * (1.0f/1024.0f) + EPSc);
  float4 wv = ((const float4*)w)[t];
  float4 gv = ((const float4*)gamma)[t];
  float4 bv = ((const float4*)beta)[t];
  bf16x4 o;
  o[0] = (bf16)(v.x*r*wv.x*gv.x + bv.x);
  o[1] = (bf16)(v.y*r*wv.y*gv.y + bv.y);
  o[2] = (bf16)(v.z*r*wv.z*gv.z + bv.z);
  o[3] = (bf16)(v.w*r*wv.w*gv.w + bv.w);
  *(bf16x4*)&out[(size_t)row*1024 + t*4] = o;
}

// ---------------- 128-tile GEMM: C[M,N] = A[M,K]*B[N,K]^T, T2-swizzled LDS -----------
// EP: 0 = store bf16; 1 = fp32 + auxf residual; 4 = x+(xa+acc-x)*iter_scale
template<int EP, int NTW>
__global__ __launch_bounds__(256)
void gemm_bt(const bf16* __restrict__ A, const bf16* __restrict__ Bw,
             int M, int N, int K, int lda, int ldb, int gx,
             float* __restrict__ outf, bf16* __restrict__ outb,
             const float* __restrict__ auxf, const float* __restrict__ auxf2,
             const float* __restrict__ iscale) {
  constexpr int BN = NTW * 32;
  __shared__ __align__(16) bf16 As[2][128*64];
  __shared__ __align__(16) bf16 Bs[2][BN*64];
  const int nwg = gridDim.x;
  const int orig = blockIdx.x;
  const int wg = (orig & 7) * (nwg >> 3) + (orig >> 3);
  const int tn0 = (wg % gx) * BN, tm0 = (wg / gx) * 128;
  const int tid = threadIdx.x, wave = tid >> 6, lane = tid & 63;
  const int lr = lane & 15, lg = lane >> 4;
  const int wr = wave >> 1, wc = wave & 1;
  f32x4 acc[4][NTW] = {};
  const int rs = lane >> 3;
  const int sc = (((lane & 7) ^ rs) << 3);          // pre-swizzled source col offset
  const int x0 = ((lg ^ (lr & 7)) << 3);            // swizzled read col, kk=0
  const int x1 = (((4 + lg) ^ (lr & 7)) << 3);      // kk=1

  const bf16* Abase = A + (size_t)tm0 * lda;
  const bf16* Bbase = Bw + (size_t)tn0 * ldb;

  auto stage = [&](bf16* as, bf16* bs, int k0) {
    #pragma unroll
    for (int j = 0; j < 4; ++j) {
      int chunk = wave*4 + j;
      int r = chunk*8 + rs;
      glds16(Abase + (size_t)r*lda + k0 + sc, as + chunk*512 + lane*8);
    }
    #pragma unroll
    for (int j = 0; j < NTW; ++j) {
      int chunk = wave*NTW + j;
      int r = chunk*8 + rs;
      glds16(Bbase + (size_t)r*ldb + k0 + sc, bs + chunk*512 + lane*8);
    }
  };
  auto comp = [&](const bf16* as, const bf16* bs) {
    #pragma unroll
    for (int kk = 0; kk < 2; ++kk) {
      const int x = kk ? x1 : x0;
      bf16x8 av[4], bv[NTW];
      #pragma unroll
      for (int m = 0; m < 4; ++m) av[m] = *(const bf16x8*)&as[(wr*64 + m*16 + lr)*64 + x];
      #pragma unroll
      for (int n = 0; n < NTW; ++n) bv[n] = *(const bf16x8*)&bs[(wc*NTW*16 + n*16 + lr)*64 + x];
      #pragma unroll
      for (int m = 0; m < 4; ++m)
        #pragma unroll
        for (int n = 0; n < NTW; ++n)
          acc[m][n] = __builtin_amdgcn_mfma_f32_16x16x32_bf16(av[m], bv[n], acc[m][n], 0, 0, 0);
    }
  };

  bf16 *a0 = As[0], *a1 = As[1], *b0 = Bs[0], *b1 = Bs[1];
  stage(a0, b0, 0);
  __syncthreads();
  for (int k0 = 64; k0 < K; k0 += 64) {
    stage(a1, b1, k0);
    comp(a0, b0);
    __syncthreads();
    bf16* t;
    t = a0; a0 = a1; a1 = t;
    t = b0; b0 = b1; b1 = t;
  }
  comp(a0, b0);

  float its = 0.f;
  if constexpr (EP == 4) its = iscale[0];
  #pragma unroll
  for (int m = 0; m < 4; ++m)
    #pragma unroll
    for (int n = 0; n < NTW; ++n)
      #pragma unroll
      for (int i = 0; i < 4; ++i) {
        int row = tm0 + wr*64 + m*16 + lg*4 + i;
        int col = tn0 + wc*NTW*16 + n*16 + lr;
        size_t idx = (size_t)row * N + col;
        float v = acc[m][n][i];
        if constexpr (EP == 0) outb[idx] = (bf16)v;
        else if constexpr (EP == 1) outf[idx] = auxf[idx] + v;
        else if constexpr (EP == 4) {
          float xv = auxf[idx], xa = auxf2[idx];
          outf[idx] = xv + (xa + v - xv) * its;
        }
      }
}

// ---- 256x256 pipelined GEMM for gate/up (M=2048 N=8192 K=1024), fused silu epilogue -
// 8 waves (2M x 4N), 128KB LDS = 2 K-tile buffers, 4 phases/K-tile, one half-tile
// staged per phase, counted vmcnt(4) (never 0 mid-loop), T2 swizzle, T5 setprio.
__global__ __launch_bounds__(512, 2)
void gemm_gu256(const bf16* __restrict__ A, const bf16* __restrict__ Bw,
                bf16* __restrict__ outb) {
  __shared__ __align__(16) bf16 L[2][2][2][8192];   // [buf][op A0/B1][half][128*64]
  const int orig = blockIdx.x;
  const int wg = (orig & 7) * 32 + (orig >> 3);     // 256 blocks, bijective XCD swizzle
  const int tn0 = (wg & 31) * 256, tm0 = (wg >> 5) * 256;
  const int tid = threadIdx.x, wave = tid >> 6, lane = tid & 63;
  const int lr = lane & 15, lg = lane >> 4;
  const int wr = wave >> 2, wn = wave & 3;
  const int rs8 = lane >> 3;
  const int gc8 = (((lane & 7) ^ rs8) << 3);        // pre-swizzled global col offset
  const int xk0 = ((lg ^ (lr & 7)) << 3);
  const int xk1 = (((4 + lg) ^ (lr & 7)) << 3);
  f32x4 acc[8][4] = {};

  const bf16* Ab = A + (size_t)tm0 * 1024;
  const bf16* Bb = Bw + (size_t)tn0 * 1024;

  auto stage_half = [&](bf16* dst, const bf16* gbase, int half, int k0) {
    #pragma unroll
    for (int l = 0; l < 2; ++l) {
      int r = half*128 + (wave*2 + l)*8 + rs8;
      glds16(gbase + (size_t)r*1024 + k0 + gc8, dst + (wave*2 + l)*512 + lane*8);
    }
  };

  // prologue: tile0 {A0,A1,B0,B1}, tile1 {B0,B1}; wait all but last 2 halves
  stage_half(&L[0][0][0][0], Ab, 0, 0);
  stage_half(&L[0][0][1][0], Ab, 1, 0);
  stage_half(&L[0][1][0][0], Bb, 0, 0);
  stage_half(&L[0][1][1][0], Bb, 1, 0);
  stage_half(&L[1][1][0][0], Bb, 0, 64);
  stage_half(&L[1][1][1][0], Bb, 1, 64);
  asm volatile("s_waitcnt vmcnt(4)" ::: "memory");
  __builtin_amdgcn_s_barrier();

  for (int t = 0; t < 16; ++t) {
    const int b = t & 1;
    const bf16* ah = &L[b][0][wr][0];
    const bf16* bh = &L[b][1][wn >> 1][0];
    bf16x8 breg[4][2];
    #pragma unroll
    for (int p = 0; p < 4; ++p) {
      if (p == 0) {                          // B fragments -> regs (frees B LDS region)
        #pragma unroll
        for (int n = 0; n < 4; ++n) {
          int row = (wn & 1)*64 + n*16 + lr;
          breg[n][0] = *(const bf16x8*)&bh[row*64 + xk0];
          breg[n][1] = *(const bf16x8*)&bh[row*64 + xk1];
        }
      }
      bf16x8 av[2][2];
      #pragma unroll
      for (int mi = 0; mi < 2; ++mi) {
        int row = p*32 + mi*16 + lr;
        av[mi][0] = *(const bf16x8*)&ah[row*64 + xk0];
        av[mi][1] = *(const bf16x8*)&ah[row*64 + xk1];
      }
      // stage schedule: A(t+1) at p0/p1 (other buf, dead); B(t+2) at p2/p3
      // (this buf's B region, consumed into regs at p0)
      if (p == 0 && t < 15) stage_half(&L[b^1][0][0][0], Ab, 0, (t+1)*64);
      if (p == 1 && t < 15) stage_half(&L[b^1][0][1][0], Ab, 1, (t+1)*64);
      if (p == 2 && t < 14) stage_half(&L[b][1][0][0], Bb, 0, (t+2)*64);
      if (p == 3 && t < 14) stage_half(&L[b][1][1][0], Bb, 1, (t+2)*64);
      __builtin_amdgcn_s_barrier();
      __builtin_amdgcn_s_setprio(1);
      #pragma unroll
      for (int mi = 0; mi < 2; ++mi)
        #pragma unroll
        for (int n = 0; n < 4; ++n) {
          acc[p*2+mi][n] = __builtin_amdgcn_mfma_f32_16x16x32_bf16(av[mi][0], breg[n][0], acc[p*2+mi][n], 0, 0, 0);
          acc[p*2+mi][n] = __builtin_amdgcn_mfma_f32_16x16x32_bf16(av[mi][1], breg[n][1], acc[p*2+mi][n], 0, 0, 0);
        }
      __builtin_amdgcn_s_setprio(0);
      if (p == 3) {
        if (t >= 14) asm volatile("s_waitcnt vmcnt(0)" ::: "memory");
        else         asm volatile("s_waitcnt vmcnt(4)" ::: "memory");
      }
      __builtin_amdgcn_s_barrier();
    }
  }

  // epilogue: silu(gate)*up; n pairs (0,1),(2,3); out [2048][4096]
  #pragma unroll
  for (int mf = 0; mf < 8; ++mf)
    #pragma unroll
    for (int j = 0; j < 2; ++j)
      #pragma unroll
      for (int i = 0; i < 4; ++i) {
        int row = tm0 + wr*128 + mf*16 + lg*4 + i;
        int col = (tn0 >> 1) + wn*32 + j*16 + lr;
        float g = acc[mf][2*j][i], u = acc[mf][2*j+1][i];
        float s = g / (1.f + __builtin_amdgcn_exp2f(-g * LOG2E));
        outb[(size_t)row * 4096 + col] = (bf16)(s * u);
      }
}

// ---- mega-kernel: gu/down weight combine (bids 0..255) + flash attention ------------
__global__ __launch_bounds__(256)
void attn_mega(const bf16* __restrict__ qkv, bf16* __restrict__ out,
               const float* __restrict__ gate_b, const float* __restrict__ up_b,
               const float* __restrict__ down_b,
               const float* __restrict__ a_gate, const float* __restrict__ a_up,
               const float* __restrict__ a_down, const int* __restrict__ lidx,
               bf16* __restrict__ Wgu, bf16* __restrict__ Wd) {
  __shared__ __align__(16) bf16 Ks[2][64*72];
  __shared__ __align__(16) bf16 Vt[2][64*66];
  __shared__ __align__(16) bf16 Ps[4][16*68];
  const int bid = blockIdx.x;
  const int tid = threadIdx.x;

  if (bid < 256) {
    const int cb = bid;
    int li = lidx[0];
    float g0 = a_gate[li*4], g1 = a_gate[li*4+1], g2 = a_gate[li*4+2], g3 = a_gate[li*4+3];
    float u0 = a_up[li*4],   u1 = a_up[li*4+1],   u2 = a_up[li*4+2],   u3 = a_up[li*4+3];
    float d0 = a_down[li*4], d1 = a_down[li*4+1], d2 = a_down[li*4+2], d3 = a_down[li*4+3];
    const size_t PS = (size_t)4096 * 1024;
    for (int it = 0; it < 48; ++it) {
      int chunk = it * 256 + cb;
      if (chunk < 8192) {
        int r = chunk, w = r & 31;
        int f = ((r >> 5) << 4) + (w & 15);
        const float* base = (w < 16) ? gate_b : up_b;
        float a0 = (w < 16) ? g0 : u0, a1 = (w < 16) ? g1 : u1;
        float a2 = (w < 16) ? g2 : u2, a3 = (w < 16) ? g3 : u3;
        size_t src = (size_t)f*1024 + tid*4;
        bf16x4 o = comb4(base+src, base+PS+src, base+2*PS+src, base+3*PS+src, a0, a1, a2, a3);
        *(bf16x4*)&Wgu[((size_t)r << 10) + tid*4] = o;
      } else {
        size_t off = ((size_t)(chunk - 8192) << 10) + tid*4;
        bf16x4 o = comb4(down_b+off, down_b+PS+off, down_b+2*PS+off, down_b+3*PS+off, d0, d1, d2, d3);
        *(bf16x4*)&Wd[off] = o;
      }
    }
    return;
  }

  const int a = bid - 256;
  const int qb = 31 - (a >> 4);
  const int h = (a & 7) + 8 * ((a >> 3) & 1);
  const int wave = tid >> 6, lane = tid & 63;
  const int lr = lane & 15, lg = lane >> 4;
  const int q0 = qb * 64;

  bf16x8 qf[2];
  {
    const bf16* qrow = qkv + (size_t)(q0 + wave*16 + lr)*3072 + h*64;
    qf[0] = *(const bf16x8*)(qrow + lg*8);
    qf[1] = *(const bf16x8*)(qrow + 32 + lg*8);
  }
  f32x4 o[4] = {};
  float mrow[4], lrow[4];
  #pragma unroll
  for (int i = 0; i < 4; ++i) { mrow[i] = -__builtin_inff(); lrow[i] = 0.f; }

  const int r0 = tid >> 3, r1 = (tid + 256) >> 3;
  const int c0 = (tid & 7) << 3;
  const bf16* kb = qkv + 1024 + h*64 + c0;
  const bf16* vb = qkv + 2048 + h*64 + c0;

  bf16x8 kreg[2], vreg[2];
  auto stage_load = [&](int kv0) {
    kreg[0] = *(const bf16x8*)(kb + (size_t)(kv0 + r0)*3072);
    kreg[1] = *(const bf16x8*)(kb + (size_t)(kv0 + r1)*3072);
    vreg[0] = *(const bf16x8*)(vb + (size_t)(kv0 + r0)*3072);
    vreg[1] = *(const bf16x8*)(vb + (size_t)(kv0 + r1)*3072);
  };
  auto stage_write = [&](int buf) {
    *(bf16x8*)&Ks[buf][r0*72 + c0] = kreg[0];
    *(bf16x8*)&Ks[buf][r1*72 + c0] = kreg[1];
    #pragma unroll
    for (int e = 0; e < 8; ++e) Vt[buf][(c0 + e)*66 + r0] = vreg[0][e];
    #pragma unroll
    for (int e = 0; e < 8; ++e) Vt[buf][(c0 + e)*66 + r1] = vreg[1][e];
  };

  stage_load(0);
  stage_write(0);
  __syncthreads();
  int cur = 0;

  const float C = 0.125f * LOG2E;

  for (int t = 0; t <= qb; ++t) {
    const int kv0 = t * 64;
    if (t < qb) stage_load(kv0 + 64);

    f32x4 s[4] = {};
    __builtin_amdgcn_s_setprio(1);
    #pragma unroll
    for (int n = 0; n < 4; ++n) {
      bf16x8 k0f = *(const bf16x8*)&Ks[cur][(n*16 + lr)*72 + lg*8];
      s[n] = __builtin_amdgcn_mfma_f32_16x16x32_bf16(qf[0], k0f, s[n], 0, 0, 0);
      bf16x8 k1f = *(const bf16x8*)&Ks[cur][(n*16 + lr)*72 + 32 + lg*8];
      s[n] = __builtin_amdgcn_mfma_f32_16x16x32_bf16(qf[1], k1f, s[n], 0, 0, 0);
    }
    __builtin_amdgcn_s_setprio(0);

    if (t == qb) {
      const int qbase = q0 + wave*16 + lg*4;
      #pragma unroll
      for (int n = 0; n < 4; ++n)
        #pragma unroll
        for (int i = 0; i < 4; ++i)
          if (kv0 + n*16 + lr > qbase + i) s[n][i] = -__builtin_inff();
    }

    float mnewr[4], pmn[4];
    #pragma unroll
    for (int i = 0; i < 4; ++i) mnewr[i] = fmaxf(fmaxf(s[0][i], s[1][i]), fmaxf(s[2][i], s[3][i]));
    #pragma unroll
    for (int i = 0; i < 4; ++i)
      #pragma unroll
      for (int off = 1; off < 16; off <<= 1) mnewr[i] = fmaxf(mnewr[i], __shfl_xor(mnewr[i], off, 64));
    bool grow = false;
    #pragma unroll
    for (int i = 0; i < 4; ++i) { pmn[i] = mnewr[i] * C; grow = grow || (pmn[i] > mrow[i] + 8.f); }
    if (__any(grow)) {
      #pragma unroll
      for (int i = 0; i < 4; ++i) {
        float mt = fmaxf(mrow[i], pmn[i]);
        float fc = __builtin_amdgcn_exp2f(mrow[i] - mt);
        mrow[i] = mt;
        lrow[i] *= fc;
        #pragma unroll
        for (int nd = 0; nd < 4; ++nd) o[nd][i] *= fc;
      }
    }
    float rsum[4] = {0.f, 0.f, 0.f, 0.f};
    #pragma unroll
    for (int n = 0; n < 4; ++n)
      #pragma unroll
      for (int i = 0; i < 4; ++i) {
        float e = __builtin_amdgcn_exp2f(__builtin_fmaf(s[n][i], C, -mrow[i]));
        s[n][i] = e;
        rsum[i] += e;
      }
    #pragma unroll
    for (int i = 0; i < 4; ++i)
      #pragma unroll
      for (int off = 1; off < 16; off <<= 1) rsum[i] += __shfl_xor(rsum[i], off, 64);
    #pragma unroll
    for (int i = 0; i < 4; ++i) lrow[i] += rsum[i];
    #pragma unroll
    for (int n = 0; n < 4; ++n)
      #pragma unroll
      for (int i = 0; i < 4; ++i) Ps[wave][(lg*4 + i)*68 + n*16 + lr] = (bf16)s[n][i];
    asm volatile("s_waitcnt lgkmcnt(0)" ::: "memory");
    __builtin_amdgcn_s_setprio(1);
    #pragma unroll
    for (int kk = 0; kk < 2; ++kk) {
      bf16x8 pf = *(const bf16x8*)&Ps[wave][lr*68 + kk*32 + lg*8];
      #pragma unroll
      for (int nd = 0; nd < 4; ++nd) {
        bf16x8 vf = *(const bf16x8*)&Vt[cur][(nd*16 + lr)*66 + kk*32 + lg*8];
        o[nd] = __builtin_amdgcn_mfma_f32_16x16x32_bf16(pf, vf, o[nd], 0, 0, 0);
      }
    }
    __builtin_amdgcn_s_setprio(0);
    if (t < qb) {
      stage_write(cur ^ 1);
      __syncthreads();
      cur ^= 1;
    }
  }
  #pragma unroll
  for (int i = 0; i < 4; ++i) {
    float inv = 1.f / lrow[i];
    #pragma unroll
    for (int nd = 0; nd < 4; ++nd)
      out[(size_t)(q0 + wave*16 + lg*4 + i)*1024 + h*64 + nd*16 + lr] = (bf16)(o[nd][i]*inv);
  }
}

extern "C" void kernel_launch(void* const* d_in, const int* in_sizes, int n_in,
                              void* d_out, int out_size, void* d_ws, size_t ws_size,
                              hipStream_t stream) {
  const float* x        = (const float*)d_in[0];
  const float* gamma    = (const float*)d_in[1];
  const float* beta     = (const float*)d_in[2];
  const float* iscale   = (const float*)d_in[3];
  const float* qkv_b    = (const float*)d_in[4];
  const float* o_b      = (const float*)d_in[5];
  const float* gate_b   = (const float*)d_in[6];
  const float* up_b     = (const float*)d_in[7];
  const float* down_b   = (const float*)d_in[8];
  const float* a_qkv    = (const float*)d_in[9];
  const float* a_o      = (const float*)d_in[10];
  const float* a_gate   = (const float*)d_in[11];
  const float* a_up     = (const float*)d_in[12];
  const float* a_down   = (const float*)d_in[13];
  const float* n1w      = (const float*)d_in[14];
  const float* n2w      = (const float*)d_in[15];
  const int*   lidx     = (const int*)d_in[16];

  char* p = (char*)d_ws;
  auto alloc = [&](size_t bytes) { char* r = p; p += (bytes + 255) & ~(size_t)255; return r; };
  bf16*  Wqkv = (bf16*)alloc((size_t)3072*1024*2);
  bf16*  Wo   = (bf16*)alloc((size_t)1024*1024*2);
  bf16*  Wgu  = (bf16*)alloc((size_t)8192*1024*2);
  bf16*  Wd   = (bf16*)alloc((size_t)1024*4096*2);
  bf16*  hbuf = (bf16*)alloc((size_t)2048*1024*2);
  bf16*  qkvb = (bf16*)alloc((size_t)2048*3072*2);
  bf16*  attn = (bf16*)alloc((size_t)2048*1024*2);
  float* xat  = (float*)alloc((size_t)2048*1024*4);
  bf16*  h2   = (bf16*)alloc((size_t)2048*1024*2);
  bf16*  act  = (bf16*)alloc((size_t)2048*4096*2);
  float* out  = (float*)d_out;

  prep1<<<6144, 256, 0, stream>>>(qkv_b, a_qkv, o_b, a_o, x, n1w, gamma, beta, lidx,
                                  Wqkv, Wo, hbuf);
  gemm_bt<0,4><<<24*16, 256, 0, stream>>>(hbuf, Wqkv, 2048, 3072, 1024, 1024, 1024, 24,
                                          nullptr, qkvb, nullptr, nullptr, nullptr);
  attn_mega<<<768, 256, 0, stream>>>(qkvb, attn, gate_b, up_b, down_b,
                                     a_gate, a_up, a_down, lidx, Wgu, Wd);
  gemm_bt<1,2><<<16*16, 256, 0, stream>>>(attn, Wo, 2048, 1024, 1024, 1024, 1024, 16,
                                          xat, nullptr, x, nullptr, nullptr);
  rmsnorm_k<<<2048, 256, 0, stream>>>(xat, n2w, gamma, beta, h2);
  gemm_gu256<<<256, 512, 0, stream>>>(h2, Wgu, act);
  gemm_bt<4,2><<<16*16, 256, 0, stream>>>(act, Wd, 2048, 1024, 4096, 4096, 4096, 16,
                                          out, nullptr, x, xat, iscale);
}

// Round 7
// 193.460 us; speedup vs baseline: 1.2140x; 1.0543x over previous
//
#include <hip/hip_runtime.h>
#include <hip/hip_bf16.h>
#include <math.h>

typedef __bf16 bf16;
typedef __bf16 bf16x8 __attribute__((ext_vector_type(8)));
typedef __bf16 bf16x4 __attribute__((ext_vector_type(4)));
typedef float f32x4 __attribute__((ext_vector_type(4)));

#define EPSc 1.1920929e-07f
#define LOG2E 1.44269504f

static __device__ __forceinline__ void glds16(const void* g, void* l) {
  __builtin_amdgcn_global_load_lds((const __attribute__((address_space(1))) void*)g,
                                   (__attribute__((address_space(3))) void*)l, 16, 0, 0);
}

static __device__ __forceinline__ bf16x4 comb4(const float* b0, const float* b1,
                                               const float* b2, const float* b3,
                                               float a0, float a1, float a2, float a3) {
  float4 v0 = *(const float4*)b0, v1 = *(const float4*)b1;
  float4 v2 = *(const float4*)b2, v3 = *(const float4*)b3;
  bf16x4 o;
  o[0] = (bf16)(a0*v0.x + a1*v1.x + a2*v2.x + a3*v3.x);
  o[1] = (bf16)(a0*v0.y + a1*v1.y + a2*v2.y + a3*v3.y);
  o[2] = (bf16)(a0*v0.z + a1*v1.z + a2*v2.z + a3*v3.z);
  o[3] = (bf16)(a0*v0.w + a1*v1.w + a2*v2.w + a3*v3.w);
  return o;
}

// ---- prep1: fused combine_qkv + combine_o + rmsnorm1 (all independent) -------------
__global__ __launch_bounds__(256)
void prep1(const float* __restrict__ qkv_b, const float* __restrict__ a_qkv,
           const float* __restrict__ o_b,   const float* __restrict__ a_o,
           const float* __restrict__ x, const float* __restrict__ n1w,
           const float* __restrict__ gamma, const float* __restrict__ beta,
           const int* __restrict__ lidx,
           bf16* __restrict__ Wqkv, bf16* __restrict__ Wo, bf16* __restrict__ hbuf) {
  const int bid = blockIdx.x, tid = threadIdx.x;
  if (bid < 4096) {
    int li = lidx[0];
    const float* base; const float* al; bf16* out; size_t flat, n;
    if (bid < 3072) { base = qkv_b; al = a_qkv; out = Wqkv; flat = (size_t)bid << 10; n = (size_t)3072*1024; }
    else            { base = o_b;   al = a_o;   out = Wo;   flat = (size_t)(bid-3072) << 10; n = (size_t)1024*1024; }
    float a0 = al[li*4], a1 = al[li*4+1], a2 = al[li*4+2], a3 = al[li*4+3];
    size_t off = flat + tid*4;
    bf16x4 o = comb4(base+off, base+n+off, base+2*n+off, base+3*n+off, a0, a1, a2, a3);
    *(bf16x4*)&out[off] = o;
  } else {
    int row = bid - 4096, t = tid;
    const float4* xr = (const float4*)(x + (size_t)row*1024);
    float4 v = xr[t];
    float ss = v.x*v.x + v.y*v.y + v.z*v.z + v.w*v.w;
    #pragma unroll
    for (int off = 32; off > 0; off >>= 1) ss += __shfl_down(ss, off, 64);
    __shared__ float red[4];
    if ((t & 63) == 0) red[t >> 6] = ss;
    __syncthreads();
    float tot = red[0] + red[1] + red[2] + red[3];
    float r = rsqrtf(tot * (1.0f/1024.0f) + EPSc);
    float4 wv = ((const float4*)n1w)[t];
    float4 gv = ((const float4*)gamma)[t];
    float4 bv = ((const float4*)beta)[t];
    bf16x4 o;
    o[0] = (bf16)(v.x*r*wv.x*gv.x + bv.x);
    o[1] = (bf16)(v.y*r*wv.y*gv.y + bv.y);
    o[2] = (bf16)(v.z*r*wv.z*gv.z + bv.z);
    o[3] = (bf16)(v.w*r*wv.w*gv.w + bv.w);
    *(bf16x4*)&hbuf[(size_t)row*1024 + t*4] = o;
  }
}

// ---------------- rmsnorm (standalone, for norm2) ------------------------------------
__global__ __launch_bounds__(256) void rmsnorm_k(const float* __restrict__ x,
                                                 const float* __restrict__ w,
                                                 const float* __restrict__ gamma,
                                                 const float* __restrict__ beta,
                                                 bf16* __restrict__ out) {
  int row = blockIdx.x, t = threadIdx.x;
  const float4* xr = (const float4*)(x + (size_t)row*1024);
  float4 v = xr[t];
  float ss = v.x*v.x + v.y*v.y + v.z*v.z + v.w*v.w;
  #pragma unroll
  for (int off = 32; off > 0; off >>= 1) ss += __shfl_down(ss, off, 64);
  __shared__ float red[4];
  if ((t & 63) == 0) red[t >> 6] = ss;
  __syncthreads();
  float tot = red[0] + red[1] + red[2] + red[3];
  float r = rsqrtf(tot * (1.0f/1024.0f) + EPSc);
  float4 wv = ((const float4*)w)[t];
  float4 gv = ((const float4*)gamma)[t];
  float4 bv = ((const float4*)beta)[t];
  bf16x4 o;
  o[0] = (bf16)(v.x*r*wv.x*gv.x + bv.x);
  o[1] = (bf16)(v.y*r*wv.y*gv.y + bv.y);
  o[2] = (bf16)(v.z*r*wv.z*gv.z + bv.z);
  o[3] = (bf16)(v.w*r*wv.w*gv.w + bv.w);
  *(bf16x4*)&out[(size_t)row*1024 + t*4] = o;
}

// ---------------- 128-tile GEMM: C[M,N] = A[M,K]*B[N,K]^T, T2-swizzled LDS -----------
template<int EP, int NTW>
__global__ __launch_bounds__(256)
void gemm_bt(const bf16* __restrict__ A, const bf16* __restrict__ Bw,
             int M, int N, int K, int lda, int ldb, int gx,
             float* __restrict__ outf, bf16* __restrict__ outb,
             const float* __restrict__ auxf, const float* __restrict__ auxf2,
             const float* __restrict__ iscale) {
  constexpr int BN = NTW * 32;
  __shared__ __align__(16) bf16 As[2][128*64];
  __shared__ __align__(16) bf16 Bs[2][BN*64];
  const int nwg = gridDim.x;
  const int orig = blockIdx.x;
  const int wg = (orig & 7) * (nwg >> 3) + (orig >> 3);
  const int tn0 = (wg % gx) * BN, tm0 = (wg / gx) * 128;
  const int tid = threadIdx.x, wave = tid >> 6, lane = tid & 63;
  const int lr = lane & 15, lg = lane >> 4;
  const int wr = wave >> 1, wc = wave & 1;
  f32x4 acc[4][NTW] = {};
  const int rs = lane >> 3;
  const int sc = (((lane & 7) ^ rs) << 3);
  const int x0 = ((lg ^ (lr & 7)) << 3);
  const int x1 = (((4 + lg) ^ (lr & 7)) << 3);

  const bf16* Abase = A + (size_t)tm0 * lda;
  const bf16* Bbase = Bw + (size_t)tn0 * ldb;

  auto stage = [&](bf16* as, bf16* bs, int k0) {
    #pragma unroll
    for (int j = 0; j < 4; ++j) {
      int chunk = wave*4 + j;
      int r = chunk*8 + rs;
      glds16(Abase + (size_t)r*lda + k0 + sc, as + chunk*512 + lane*8);
    }
    #pragma unroll
    for (int j = 0; j < NTW; ++j) {
      int chunk = wave*NTW + j;
      int r = chunk*8 + rs;
      glds16(Bbase + (size_t)r*ldb + k0 + sc, bs + chunk*512 + lane*8);
    }
  };
  auto comp = [&](const bf16* as, const bf16* bs) {
    #pragma unroll
    for (int kk = 0; kk < 2; ++kk) {
      const int x = kk ? x1 : x0;
      bf16x8 av[4], bv[NTW];
      #pragma unroll
      for (int m = 0; m < 4; ++m) av[m] = *(const bf16x8*)&as[(wr*64 + m*16 + lr)*64 + x];
      #pragma unroll
      for (int n = 0; n < NTW; ++n) bv[n] = *(const bf16x8*)&bs[(wc*NTW*16 + n*16 + lr)*64 + x];
      #pragma unroll
      for (int m = 0; m < 4; ++m)
        #pragma unroll
        for (int n = 0; n < NTW; ++n)
          acc[m][n] = __builtin_amdgcn_mfma_f32_16x16x32_bf16(av[m], bv[n], acc[m][n], 0, 0, 0);
    }
  };

  bf16 *a0 = As[0], *a1 = As[1], *b0 = Bs[0], *b1 = Bs[1];
  stage(a0, b0, 0);
  __syncthreads();
  for (int k0 = 64; k0 < K; k0 += 64) {
    stage(a1, b1, k0);
    comp(a0, b0);
    __syncthreads();
    bf16* t;
    t = a0; a0 = a1; a1 = t;
    t = b0; b0 = b1; b1 = t;
  }
  comp(a0, b0);

  float its = 0.f;
  if constexpr (EP == 4) its = iscale[0];
  #pragma unroll
  for (int m = 0; m < 4; ++m)
    #pragma unroll
    for (int n = 0; n < NTW; ++n)
      #pragma unroll
      for (int i = 0; i < 4; ++i) {
        int row = tm0 + wr*64 + m*16 + lg*4 + i;
        int col = tn0 + wc*NTW*16 + n*16 + lr;
        size_t idx = (size_t)row * N + col;
        float v = acc[m][n][i];
        if constexpr (EP == 0) outb[idx] = (bf16)v;
        else if constexpr (EP == 1) outf[idx] = auxf[idx] + v;
        else if constexpr (EP == 4) {
          float xv = auxf[idx], xa = auxf2[idx];
          outf[idx] = xv + (xa + v - xv) * its;
        }
      }
}

// ---- 256x256 pipelined GEMM for gate/up (M=2048 N=8192 K=1024), fused silu epilogue -
__global__ __launch_bounds__(512, 2)
void gemm_gu256(const bf16* __restrict__ A, const bf16* __restrict__ Bw,
                bf16* __restrict__ outb) {
  __shared__ __align__(16) bf16 L[2][2][2][8192];
  const int orig = blockIdx.x;
  const int wg = (orig & 7) * 32 + (orig >> 3);
  const int tn0 = (wg & 31) * 256, tm0 = (wg >> 5) * 256;
  const int tid = threadIdx.x, wave = tid >> 6, lane = tid & 63;
  const int lr = lane & 15, lg = lane >> 4;
  const int wr = wave >> 2, wn = wave & 3;
  const int rs8 = lane >> 3;
  const int gc8 = (((lane & 7) ^ rs8) << 3);
  const int xk0 = ((lg ^ (lr & 7)) << 3);
  const int xk1 = (((4 + lg) ^ (lr & 7)) << 3);
  f32x4 acc[8][4] = {};

  const bf16* Ab = A + (size_t)tm0 * 1024;
  const bf16* Bb = Bw + (size_t)tn0 * 1024;

  auto stage_half = [&](bf16* dst, const bf16* gbase, int half, int k0) {
    #pragma unroll
    for (int l = 0; l < 2; ++l) {
      int r = half*128 + (wave*2 + l)*8 + rs8;
      glds16(gbase + (size_t)r*1024 + k0 + gc8, dst + (wave*2 + l)*512 + lane*8);
    }
  };

  stage_half(&L[0][0][0][0], Ab, 0, 0);
  stage_half(&L[0][0][1][0], Ab, 1, 0);
  stage_half(&L[0][1][0][0], Bb, 0, 0);
  stage_half(&L[0][1][1][0], Bb, 1, 0);
  stage_half(&L[1][1][0][0], Bb, 0, 64);
  stage_half(&L[1][1][1][0], Bb, 1, 64);
  asm volatile("s_waitcnt vmcnt(4)" ::: "memory");
  __builtin_amdgcn_s_barrier();

  for (int t = 0; t < 16; ++t) {
    const int b = t & 1;
    const bf16* ah = &L[b][0][wr][0];
    const bf16* bh = &L[b][1][wn >> 1][0];
    bf16x8 breg[4][2];
    #pragma unroll
    for (int p = 0; p < 4; ++p) {
      if (p == 0) {
        #pragma unroll
        for (int n = 0; n < 4; ++n) {
          int row = (wn & 1)*64 + n*16 + lr;
          breg[n][0] = *(const bf16x8*)&bh[row*64 + xk0];
          breg[n][1] = *(const bf16x8*)&bh[row*64 + xk1];
        }
      }
      bf16x8 av[2][2];
      #pragma unroll
      for (int mi = 0; mi < 2; ++mi) {
        int row = p*32 + mi*16 + lr;
        av[mi][0] = *(const bf16x8*)&ah[row*64 + xk0];
        av[mi][1] = *(const bf16x8*)&ah[row*64 + xk1];
      }
      if (p == 0 && t < 15) stage_half(&L[b^1][0][0][0], Ab, 0, (t+1)*64);
      if (p == 1 && t < 15) stage_half(&L[b^1][0][1][0], Ab, 1, (t+1)*64);
      if (p == 2 && t < 14) stage_half(&L[b][1][0][0], Bb, 0, (t+2)*64);
      if (p == 3 && t < 14) stage_half(&L[b][1][1][0], Bb, 1, (t+2)*64);
      __builtin_amdgcn_s_barrier();
      __builtin_amdgcn_s_setprio(1);
      #pragma unroll
      for (int mi = 0; mi < 2; ++mi)
        #pragma unroll
        for (int n = 0; n < 4; ++n) {
          acc[p*2+mi][n] = __builtin_amdgcn_mfma_f32_16x16x32_bf16(av[mi][0], breg[n][0], acc[p*2+mi][n], 0, 0, 0);
          acc[p*2+mi][n] = __builtin_amdgcn_mfma_f32_16x16x32_bf16(av[mi][1], breg[n][1], acc[p*2+mi][n], 0, 0, 0);
        }
      __builtin_amdgcn_s_setprio(0);
      if (p == 3) {
        if (t >= 14) asm volatile("s_waitcnt vmcnt(0)" ::: "memory");
        else         asm volatile("s_waitcnt vmcnt(4)" ::: "memory");
      }
      __builtin_amdgcn_s_barrier();
    }
  }

  #pragma unroll
  for (int mf = 0; mf < 8; ++mf)
    #pragma unroll
    for (int j = 0; j < 2; ++j)
      #pragma unroll
      for (int i = 0; i < 4; ++i) {
        int row = tm0 + wr*128 + mf*16 + lg*4 + i;
        int col = (tn0 >> 1) + wn*32 + j*16 + lr;
        float g = acc[mf][2*j][i], u = acc[mf][2*j+1][i];
        float s = g / (1.f + __builtin_amdgcn_exp2f(-g * LOG2E));
        outb[(size_t)row * 4096 + col] = (bf16)(s * u);
      }
}

// ---- mega-kernel: gu/down weight combine (bids 0..255) + flash attention ------------
// Attention uses SWAPPED QK^T: mfma(K,Q) -> lane lr owns q, all its k in-lane.
// Softmax reduce = in-lane tree + 2 shfl_xor (was 32 shfls).
__global__ __launch_bounds__(256)
void attn_mega(const bf16* __restrict__ qkv, bf16* __restrict__ out,
               const float* __restrict__ gate_b, const float* __restrict__ up_b,
               const float* __restrict__ down_b,
               const float* __restrict__ a_gate, const float* __restrict__ a_up,
               const float* __restrict__ a_down, const int* __restrict__ lidx,
               bf16* __restrict__ Wgu, bf16* __restrict__ Wd) {
  __shared__ __align__(16) bf16 Ks[2][64*72];
  __shared__ __align__(16) bf16 Vt[2][64*66];
  __shared__ __align__(16) bf16 Ps[4][16*68];
  const int bid = blockIdx.x;
  const int tid = threadIdx.x;

  if (bid < 256) {
    const int cb = bid;
    int li = lidx[0];
    float g0 = a_gate[li*4], g1 = a_gate[li*4+1], g2 = a_gate[li*4+2], g3 = a_gate[li*4+3];
    float u0 = a_up[li*4],   u1 = a_up[li*4+1],   u2 = a_up[li*4+2],   u3 = a_up[li*4+3];
    float d0 = a_down[li*4], d1 = a_down[li*4+1], d2 = a_down[li*4+2], d3 = a_down[li*4+3];
    const size_t PS = (size_t)4096 * 1024;
    for (int it = 0; it < 48; ++it) {
      int chunk = it * 256 + cb;
      if (chunk < 8192) {
        int r = chunk, w = r & 31;
        int f = ((r >> 5) << 4) + (w & 15);
        const float* base = (w < 16) ? gate_b : up_b;
        float a0 = (w < 16) ? g0 : u0, a1 = (w < 16) ? g1 : u1;
        float a2 = (w < 16) ? g2 : u2, a3 = (w < 16) ? g3 : u3;
        size_t src = (size_t)f*1024 + tid*4;
        bf16x4 o = comb4(base+src, base+PS+src, base+2*PS+src, base+3*PS+src, a0, a1, a2, a3);
        *(bf16x4*)&Wgu[((size_t)r << 10) + tid*4] = o;
      } else {
        size_t off = ((size_t)(chunk - 8192) << 10) + tid*4;
        bf16x4 o = comb4(down_b+off, down_b+PS+off, down_b+2*PS+off, down_b+3*PS+off, d0, d1, d2, d3);
        *(bf16x4*)&Wd[off] = o;
      }
    }
    return;
  }

  const int a = bid - 256;
  const int qb = 31 - (a >> 4);
  const int h = (a & 7) + 8 * ((a >> 3) & 1);
  const int wave = tid >> 6, lane = tid & 63;
  const int lr = lane & 15, lg = lane >> 4;
  const int q0 = qb * 64;

  bf16x8 qf[2];
  {
    const bf16* qrow = qkv + (size_t)(q0 + wave*16 + lr)*3072 + h*64;
    qf[0] = *(const bf16x8*)(qrow + lg*8);
    qf[1] = *(const bf16x8*)(qrow + 32 + lg*8);
  }
  f32x4 o[4] = {};
  float mrow = -__builtin_inff(), lrow = 0.f;   // per-lane: q = q0 + wave*16 + lr
  const int xsrc = (lane & 48) + ((lane >> 4) << 2);  // lane owning q = lg*4+i (i added later)

  const int r0 = tid >> 3, r1 = (tid + 256) >> 3;
  const int c0 = (tid & 7) << 3;
  const bf16* kb = qkv + 1024 + h*64 + c0;
  const bf16* vb = qkv + 2048 + h*64 + c0;

  bf16x8 kreg[2], vreg[2];
  auto stage_load = [&](int kv0) {
    kreg[0] = *(const bf16x8*)(kb + (size_t)(kv0 + r0)*3072);
    kreg[1] = *(const bf16x8*)(kb + (size_t)(kv0 + r1)*3072);
    vreg[0] = *(const bf16x8*)(vb + (size_t)(kv0 + r0)*3072);
    vreg[1] = *(const bf16x8*)(vb + (size_t)(kv0 + r1)*3072);
  };
  auto stage_write = [&](int buf) {
    *(bf16x8*)&Ks[buf][r0*72 + c0] = kreg[0];
    *(bf16x8*)&Ks[buf][r1*72 + c0] = kreg[1];
    #pragma unroll
    for (int e = 0; e < 8; ++e) Vt[buf][(c0 + e)*66 + r0] = vreg[0][e];
    #pragma unroll
    for (int e = 0; e < 8; ++e) Vt[buf][(c0 + e)*66 + r1] = vreg[1][e];
  };

  stage_load(0);
  stage_write(0);
  __syncthreads();
  int cur = 0;

  const float C = 0.125f * LOG2E;

  for (int t = 0; t <= qb; ++t) {
    const int kv0 = t * 64;
    if (t < qb) stage_load(kv0 + 64);

    // swapped QK^T: s[n] row = k_local (lg*4+i), col = q (lr)
    f32x4 s[4] = {};
    __builtin_amdgcn_s_setprio(1);
    #pragma unroll
    for (int n = 0; n < 4; ++n) {
      bf16x8 k0f = *(const bf16x8*)&Ks[cur][(n*16 + lr)*72 + lg*8];
      s[n] = __builtin_amdgcn_mfma_f32_16x16x32_bf16(k0f, qf[0], s[n], 0, 0, 0);
      bf16x8 k1f = *(const bf16x8*)&Ks[cur][(n*16 + lr)*72 + 32 + lg*8];
      s[n] = __builtin_amdgcn_mfma_f32_16x16x32_bf16(k1f, qf[1], s[n], 0, 0, 0);
    }
    __builtin_amdgcn_s_setprio(0);

    if (t == qb) {                      // diagonal tile: mask k > q
      const int qv = q0 + wave*16 + lr;
      #pragma unroll
      for (int n = 0; n < 4; ++n)
        #pragma unroll
        for (int i = 0; i < 4; ++i)
          if (kv0 + n*16 + lg*4 + i > qv) s[n][i] = -__builtin_inff();
    }

    // in-lane max over 16 values + 2 shfl (lg groups)
    float mnew;
    {
      f32x4 t0 = s[0], t1 = s[1];
      #pragma unroll
      for (int i = 0; i < 4; ++i) { t0[i] = fmaxf(t0[i], s[2][i]); t1[i] = fmaxf(t1[i], s[3][i]); }
      float a0 = fmaxf(t0[0], t0[1]), a1 = fmaxf(t0[2], t0[3]);
      float b0 = fmaxf(t1[0], t1[1]), b1 = fmaxf(t1[2], t1[3]);
      mnew = fmaxf(fmaxf(a0, a1), fmaxf(b0, b1));
    }
    mnew = fmaxf(mnew, __shfl_xor(mnew, 16, 64));
    mnew = fmaxf(mnew, __shfl_xor(mnew, 32, 64));

    float pmn = mnew * C;
    if (__any(pmn > mrow + 8.f)) {      // defer-max
      float mt = fmaxf(mrow, pmn);
      float fc = __builtin_amdgcn_exp2f(mrow - mt);
      mrow = mt;
      lrow *= fc;
      #pragma unroll
      for (int i = 0; i < 4; ++i) {
        float fci = __shfl(fc, xsrc + i, 64);   // factor for q = lg*4+i
        #pragma unroll
        for (int nd = 0; nd < 4; ++nd) o[nd][i] *= fci;
      }
    }

    float rsum = 0.f;
    #pragma unroll
    for (int n = 0; n < 4; ++n)
      #pragma unroll
      for (int i = 0; i < 4; ++i) {
        float e = __builtin_amdgcn_exp2f(__builtin_fmaf(s[n][i], C, -mrow));
        s[n][i] = e;
        rsum += e;
      }
    rsum += __shfl_xor(rsum, 16, 64);
    rsum += __shfl_xor(rsum, 32, 64);
    lrow += rsum;

    // P[q=lr][k=n*16+lg*4+i] -> Ps, 4x ds_write_b64
    #pragma unroll
    for (int n = 0; n < 4; ++n) {
      bf16x4 p4;
      #pragma unroll
      for (int i = 0; i < 4; ++i) p4[i] = (bf16)s[n][i];
      *(bf16x4*)&Ps[wave][lr*68 + n*16 + lg*4] = p4;
    }
    asm volatile("s_waitcnt lgkmcnt(0)" ::: "memory");
    __builtin_amdgcn_s_setprio(1);
    #pragma unroll
    for (int kk = 0; kk < 2; ++kk) {
      bf16x8 pf = *(const bf16x8*)&Ps[wave][lr*68 + kk*32 + lg*8];
      #pragma unroll
      for (int nd = 0; nd < 4; ++nd) {
        bf16x8 vf = *(const bf16x8*)&Vt[cur][(nd*16 + lr)*66 + kk*32 + lg*8];
        o[nd] = __builtin_amdgcn_mfma_f32_16x16x32_bf16(pf, vf, o[nd], 0, 0, 0);
      }
    }
    __builtin_amdgcn_s_setprio(0);
    if (t < qb) {
      stage_write(cur ^ 1);
      __syncthreads();
      cur ^= 1;
    }
  }
  #pragma unroll
  for (int i = 0; i < 4; ++i) {
    float li = __shfl(lrow, xsrc + i, 64);      // l for q = lg*4+i
    float inv = 1.f / li;
    #pragma unroll
    for (int nd = 0; nd < 4; ++nd)
      out[(size_t)(q0 + wave*16 + lg*4 + i)*1024 + h*64 + nd*16 + lr] = (bf16)(o[nd][i]*inv);
  }
}

extern "C" void kernel_launch(void* const* d_in, const int* in_sizes, int n_in,
                              void* d_out, int out_size, void* d_ws, size_t ws_size,
                              hipStream_t stream) {
  const float* x        = (const float*)d_in[0];
  const float* gamma    = (const float*)d_in[1];
  const float* beta     = (const float*)d_in[2];
  const float* iscale   = (const float*)d_in[3];
  const float* qkv_b    = (const float*)d_in[4];
  const float* o_b      = (const float*)d_in[5];
  const float* gate_b   = (const float*)d_in[6];
  const float* up_b     = (const float*)d_in[7];
  const float* down_b   = (const float*)d_in[8];
  const float* a_qkv    = (const float*)d_in[9];
  const float* a_o      = (const float*)d_in[10];
  const float* a_gate   = (const float*)d_in[11];
  const float* a_up     = (const float*)d_in[12];
  const float* a_down   = (const float*)d_in[13];
  const float* n1w      = (const float*)d_in[14];
  const float* n2w      = (const float*)d_in[15];
  const int*   lidx     = (const int*)d_in[16];

  char* p = (char*)d_ws;
  auto alloc = [&](size_t bytes) { char* r = p; p += (bytes + 255) & ~(size_t)255; return r; };
  bf16*  Wqkv = (bf16*)alloc((size_t)3072*1024*2);
  bf16*  Wo   = (bf16*)alloc((size_t)1024*1024*2);
  bf16*  Wgu  = (bf16*)alloc((size_t)8192*1024*2);
  bf16*  Wd   = (bf16*)alloc((size_t)1024*4096*2);
  bf16*  hbuf = (bf16*)alloc((size_t)2048*1024*2);
  bf16*  qkvb = (bf16*)alloc((size_t)2048*3072*2);
  bf16*  attn = (bf16*)alloc((size_t)2048*1024*2);
  float* xat  = (float*)alloc((size_t)2048*1024*4);
  bf16*  h2   = (bf16*)alloc((size_t)2048*1024*2);
  bf16*  act  = (bf16*)alloc((size_t)2048*4096*2);
  float* out  = (float*)d_out;

  prep1<<<6144, 256, 0, stream>>>(qkv_b, a_qkv, o_b, a_o, x, n1w, gamma, beta, lidx,
                                  Wqkv, Wo, hbuf);
  gemm_bt<0,4><<<24*16, 256, 0, stream>>>(hbuf, Wqkv, 2048, 3072, 1024, 1024, 1024, 24,
                                          nullptr, qkvb, nullptr, nullptr, nullptr);
  attn_mega<<<768, 256, 0, stream>>>(qkvb, attn, gate_b, up_b, down_b,
                                     a_gate, a_up, a_down, lidx, Wgu, Wd);
  gemm_bt<1,2><<<16*16, 256, 0, stream>>>(attn, Wo, 2048, 1024, 1024, 1024, 1024, 16,
                                          xat, nullptr, x, nullptr, nullptr);
  rmsnorm_k<<<2048, 256, 0, stream>>>(xat, n2w, gamma, beta, h2);
  gemm_gu256<<<256, 512, 0, stream>>>(h2, Wgu, act);
  gemm_bt<4,2><<<16*16, 256, 0, stream>>>(act, Wd, 2048, 1024, 4096, 4096, 4096, 16,
                                          out, nullptr, x, xat, iscale);
}